// Round 4
// baseline (434.984 us; speedup 1.0000x reference)
//
#include <hip/hip_runtime.h>
#include <math.h>

#define NMODES 32
#define NPAIR 496
#define TAYLOR_N 12

// T2 matrix in module-scope device memory (d_ws may be zero-sized).
__device__ float2 g_T2[NMODES * NMODES];

__device__ __forceinline__ float2 cmul(float2 a, float2 b) {
    return make_float2(a.x * b.x - a.y * b.y, a.x * b.y + a.y * b.x);
}

// ---------------------------------------------------------------------------
// Setup kernel: one block of 1024 threads builds T2 (32x32 complex).
// (unchanged from the round-0/3 PASSING kernels)
// ---------------------------------------------------------------------------
__global__ __launch_bounds__(1024) void setup_kernel(const float* __restrict__ params,
                                                     const float* __restrict__ kappa) {
    __shared__ float2 X[NMODES][NMODES];
    __shared__ float2 R[NMODES][NMODES];
    __shared__ float2 W[NMODES][NMODES];
    __shared__ float2 Aug[NMODES][2 * NMODES];
    __shared__ int sh_s;
    __shared__ float sh_scale;
    __shared__ int sh_piv;
    __shared__ float2 sh_pivrec;

    const int tid = threadIdx.x;
    const int i = tid >> 5;
    const int j = tid & 31;

    // --- build H ---
    float2 h;
    if (i == j) {
        float d;
        if (i < 31) {
            d = params[2 * NPAIR + i];
        } else {
            d = 0.0f;
            for (int r = 0; r < 31; ++r) d -= params[2 * NPAIR + r];
        }
        h = make_float2(d, 0.0f);
    } else {
        int a = (i < j) ? i : j;
        int b = (i < j) ? j : i;
        int idx = 31 * a - (a * (a - 1)) / 2 + (b - a - 1);  // row-major triu
        float re = params[idx];
        float im = params[NPAIR + idx];
        h = (i < j) ? make_float2(re, im) : make_float2(re, -im);
    }
    X[i][j] = h;
    __syncthreads();

    // --- inf-norm (wave 0, parallel rows + shuffle max-reduce) ---
    if (tid < 32) {
        float s = 0.0f;
        for (int c = 0; c < NMODES; ++c) {
            float2 v = X[tid][c];
            s += sqrtf(v.x * v.x + v.y * v.y);
        }
        for (int off = 16; off > 0; off >>= 1)
            s = fmaxf(s, __shfl_down(s, off));
        if (tid == 0) {
            int sc_n = 0;
            float sc = 1.0f;
            while (s > 0.25f && sc_n < 40) { s *= 0.5f; sc *= 0.5f; ++sc_n; }
            sh_s = sc_n;
            sh_scale = sc;
        }
    }
    __syncthreads();

    // --- X = (i*H) * 2^{-s} ---
    {
        float sc = sh_scale;
        float2 v = X[i][j];
        X[i][j] = make_float2(-v.y * sc, v.x * sc);
    }
    __syncthreads();

    // --- Taylor via Horner: R = I; for k=N..1: R = I + (X*R)/k ---
    R[i][j] = make_float2((i == j) ? 1.0f : 0.0f, 0.0f);
    __syncthreads();
    for (int k = TAYLOR_N; k >= 1; --k) {
        float2 acc = make_float2(0.0f, 0.0f);
        for (int kk = 0; kk < NMODES; ++kk) {
            float2 a = X[i][kk];
            float2 b = R[kk][j];
            acc.x = fmaf(a.x, b.x, fmaf(-a.y, b.y, acc.x));
            acc.y = fmaf(a.x, b.y, fmaf(a.y, b.x, acc.y));
        }
        __syncthreads();
        float invk = 1.0f / (float)k;
        R[i][j] = make_float2(((i == j) ? 1.0f : 0.0f) + acc.x * invk, acc.y * invk);
        __syncthreads();
    }

    // --- squarings ---
    {
        int s = sh_s;
        for (int q = 0; q < s; ++q) {
            float2 acc = make_float2(0.0f, 0.0f);
            for (int kk = 0; kk < NMODES; ++kk) {
                float2 a = R[i][kk];
                float2 b = R[kk][j];
                acc.x = fmaf(a.x, b.x, fmaf(-a.y, b.y, acc.x));
                acc.y = fmaf(a.x, b.y, fmaf(a.y, b.x, acc.y));
            }
            __syncthreads();
            R[i][j] = acc;
            __syncthreads();
        }
    }

    // --- W = U^T U (no conjugation) ---
    {
        float2 acc = make_float2(0.0f, 0.0f);
        for (int kk = 0; kk < NMODES; ++kk) {
            float2 a = R[kk][i];
            float2 b = R[kk][j];
            acc.x = fmaf(a.x, b.x, fmaf(-a.y, b.y, acc.x));
            acc.y = fmaf(a.x, b.y, fmaf(a.y, b.x, acc.y));
        }
        W[i][j] = acc;
    }
    __syncthreads();

    // --- augmented [1.1 I - W | W] ---
    {
        float2 w = W[i][j];
        Aug[i][j] = make_float2(((i == j) ? 1.1f : 0.0f) - w.x, -w.y);
        Aug[i][j + NMODES] = w;
    }
    __syncthreads();

    // --- Gauss-Jordan with partial pivoting; right half -> mix ---
    for (int p = 0; p < NMODES; ++p) {
        if (tid < 32) {  // parallel argmax pivot search (wave 0)
            float2 v = Aug[tid][p];
            float mag = (tid >= p) ? (v.x * v.x + v.y * v.y) : -1.0f;
            int idx = tid;
            for (int off = 16; off > 0; off >>= 1) {
                float omg = __shfl_down(mag, off);
                int oi = __shfl_down(idx, off);
                if (omg > mag) { mag = omg; idx = oi; }
            }
            if (tid == 0) sh_piv = idx;
        }
        __syncthreads();
        int piv = sh_piv;
        if (piv != p && i == p) {
            float2 a0 = Aug[p][j], b0 = Aug[piv][j];
            float2 a1 = Aug[p][j + NMODES], b1 = Aug[piv][j + NMODES];
            Aug[p][j] = b0; Aug[piv][j] = a0;
            Aug[p][j + NMODES] = b1; Aug[piv][j + NMODES] = a1;
        }
        __syncthreads();
        if (tid == 0) {
            float2 d = Aug[p][p];
            float den = d.x * d.x + d.y * d.y;
            sh_pivrec = make_float2(d.x / den, -d.y / den);
        }
        __syncthreads();
        if (i == p) {
            float2 pr = sh_pivrec;
            Aug[p][j] = cmul(Aug[p][j], pr);
            Aug[p][j + NMODES] = cmul(Aug[p][j + NMODES], pr);
        }
        __syncthreads();
        float2 f = Aug[i][p];
        __syncthreads();
        if (i != p) {
            float2 rp0 = Aug[p][j];
            float2 rp1 = Aug[p][j + NMODES];
            float2 v0 = Aug[i][j];
            float2 v1 = Aug[i][j + NMODES];
            v0.x -= f.x * rp0.x - f.y * rp0.y;
            v0.y -= f.x * rp0.y + f.y * rp0.x;
            v1.x -= f.x * rp1.x - f.y * rp1.y;
            v1.y -= f.x * rp1.y + f.y * rp1.x;
            Aug[i][j] = v0;
            Aug[i][j + NMODES] = v1;
        }
        __syncthreads();
    }

    // --- T2 ---
    {
        float2 mix = Aug[i][j + NMODES];
        float kk2 = fabsf(kappa[i]) * fabsf(kappa[j]);
        float re = -kk2 * (((i == j) ? 0.5f : 0.0f) + mix.x);
        float im = -kk2 * mix.y;
        g_T2[i * NMODES + j] = make_float2(re, im);
    }
}

// ---------------------------------------------------------------------------
// Main ODE kernel — systolic XOR-ring v3: TWO batch items per wave, chains
// interleaved for ILP.
//
// Round-3 calibration: per wave-eval = 107 plain VALU (2 cyc) + 30 dpp movs
// (~4 cyc, cross-lane network) = 334 busy-cyc — matches measured 331 exactly.
// The loss vs ideal was issue efficiency (72%): the w->dpp->w chain is serial
// and the 2 phase-locked waves/SIMD stall on the same DPP-latency bubbles.
// Fix: 1024 blocks, each wave advances batches b and b+1024 concurrently;
// the two independent DPP chains fill each other's latency gaps. Lane math,
// Gray sequence, DPP patterns, and bpermute combine are IDENTICAL to the
// round-3 passing kernel — mechanical duplication only.
// ---------------------------------------------------------------------------
template<int CTRL>
__device__ __forceinline__ float2 dppshuf(float2 v) {
    return make_float2(
        __int_as_float(__builtin_amdgcn_mov_dpp(__float_as_int(v.x), CTRL, 0xF, 0xF, true)),
        __int_as_float(__builtin_amdgcn_mov_dpp(__float_as_int(v.y), CTRL, 0xF, 0xF, true)));
}

#define QP_X1 0xB1   // quad_perm [1,0,3,2]   == xor 1
#define QP_X2 0x4E   // quad_perm [2,3,0,1]   == xor 2
#define HM_X7 0x141  // row_half_mirror       == xor 7  (within 8)
#define RM_XF 0x140  // row_mirror            == xor 15 (within 16)

__device__ __forceinline__ void cfma(float2& acc, float2 c, float2 w) {
    acc.x = fmaf(c.x, w.x, fmaf(-c.y, w.y, acc.x));
    acc.y = fmaf(c.x, w.y, fmaf(c.y, w.x, acc.y));
}

__device__ __forceinline__ float bperm(int idx, float v) {
    return __int_as_float(__builtin_amdgcn_ds_bpermute(idx, __float_as_int(v)));
}

// Two independent evals, statement-interleaved so the scheduler overlaps the
// two serial DPP chains.
__device__ __forceinline__ void feval2(const float2* __restrict__ t2,
                                       float2 z1, float2 z2,
                                       float om, float nl2,
                                       int bp0, int bp1,
                                       float2& r1, float2& r2) {
    float2 pa1 = make_float2(0.0f, 0.0f), pb1 = make_float2(0.0f, 0.0f);
    float2 pa2 = make_float2(0.0f, 0.0f), pb2 = make_float2(0.0f, 0.0f);
    float2 w1 = z1, w2 = z2;

#define RING_STEP(A1, A2, S, TRANS)                        \
    cfma(A1, t2[S], w1); cfma(A2, t2[S], w2);              \
    w1 = dppshuf<TRANS>(w1); w2 = dppshuf<TRANS>(w2);

    RING_STEP(pa1, pa2, 0,  QP_X1)   // e 0 -> 1
    RING_STEP(pb1, pb2, 1,  QP_X2)   // 1 -> 3
    RING_STEP(pa1, pa2, 2,  QP_X1)   // 3 -> 2
    RING_STEP(pb1, pb2, 3,  HM_X7)   // 2 -> 5
    RING_STEP(pa1, pa2, 4,  QP_X1)   // 5 -> 4
    RING_STEP(pb1, pb2, 5,  QP_X2)   // 4 -> 6
    RING_STEP(pa1, pa2, 6,  QP_X1)   // 6 -> 7
    RING_STEP(pb1, pb2, 7,  RM_XF)   // 7 -> 8
    RING_STEP(pa1, pa2, 8,  QP_X1)   // 8 -> 9
    RING_STEP(pb1, pb2, 9,  QP_X2)   // 9 -> 11
    RING_STEP(pa1, pa2, 10, QP_X1)   // 11 -> 10
    RING_STEP(pb1, pb2, 11, HM_X7)   // 10 -> 13
    RING_STEP(pa1, pa2, 12, QP_X1)   // 13 -> 12
    RING_STEP(pb1, pb2, 13, QP_X2)   // 12 -> 14
    RING_STEP(pa1, pa2, 14, QP_X1)   // 14 -> 15
    cfma(pb1, t2[15], w1); cfma(pb2, t2[15], w2);
#undef RING_STEP

    float px1 = pa1.x + pb1.x, py1 = pa1.y + pb1.y;
    float px2 = pa2.x + pb2.x, py2 = pa2.y + pb2.y;
    // Gather the two block-partials of this lane's owned output row:
    // partial(out-lo[p]) in lanes p and 32+p; partial(out-hi[p]) in lanes
    // 16+p and 48+p. bp0 = 4*mstar, bp1 = bp0 + 128. (round-3 proven)
    float kx1 = bperm(bp0, px1) + bperm(bp1, px1);
    float ky1 = bperm(bp0, py1) + bperm(bp1, py1);
    float kx2 = bperm(bp0, px2) + bperm(bp1, px2);
    float ky2 = bperm(bp0, py2) + bperm(bp1, py2);

    float wf1 = fmaf(nl2, fmaf(z1.x, z1.x, z1.y * z1.y), om);
    float wf2 = fmaf(nl2, fmaf(z2.x, z2.x, z2.y * z2.y), om);
    r1 = make_float2(kx1 - wf1 * z1.y, ky1 + wf1 * z1.x);
    r2 = make_float2(kx2 - wf2 * z2.y, ky2 + wf2 * z2.x);
}

__global__ __launch_bounds__(64) void ode_kernel(const float* __restrict__ A0r,
                                                 const float* __restrict__ A0i,
                                                 const float* __restrict__ omega,
                                                 const float* __restrict__ nln,
                                                 float* __restrict__ out,
                                                 long long out_size) {
    const int lane = threadIdx.x;
    const int r = lane >> 4;
    const int p = lane & 15;
    const int ho = r & 1;                       // output half this row computes
    const int hr = (r == 1 || r == 2) ? 1 : 0;  // held (ring) half
    const int mstar = 16 * hr + p;              // mode this lane owns
    const int bp0 = 4 * mstar;                  // bpermute: first partial
    const int bp1 = bp0 + 128;                  // bpermute: second partial
    const int b1 = blockIdx.x;                  // chain 1 batch
    const int b2 = b1 + 1024;                   // chain 2 batch

    // T2 block diagonal for this lane (Gray-code column order) — shared by
    // both chains.
    float2 t2[16];
    {
        const int row_g = 16 * ho + p;
        constexpr int ecol[16] = {0, 1, 3, 2, 5, 4, 6, 7, 8, 9, 11, 10, 13, 12, 14, 15};
#pragma unroll
        for (int s = 0; s < 16; ++s)
            t2[s] = g_T2[row_g * 32 + 16 * hr + (p ^ ecol[s])];
    }

    const float om = omega[mstar];
    const float nl = nln[0];
    const float nl2 = nl * nl;
    const float dt = 1.0f / 199.0f;
    const float hdt = 0.5f * dt;
    const float sdt = dt / 6.0f;

    // initial states (one LDS bounce; lanes 0-31 stage batch b1, 32-63 b2)
    __shared__ float2 ainit[64];
    {
        int q = lane & 31;
        int bb = (lane < 32) ? b1 : b2;
        float2 v;
        if (q < 24) v = make_float2(A0r[bb * 24 + q], A0i[bb * 24 + q]);
        else        v = make_float2(1.0f, 0.0f);
        ainit[lane] = v;
    }
    __syncthreads();
    float2 a1 = ainit[mstar];
    float2 a2 = ainit[32 + mstar];

    // t = 0 output (real plane only, guarded); lane l < 32 holds mode l
    long long o1 = (long long)b1 * 32 + lane;
    long long o2 = (long long)b2 * 32 + lane;
    if (lane < 32) {
        if (o1 < out_size) out[o1] = a1.x;
        if (o2 < out_size) out[o2] = a2.x;
    }

    for (int t = 1; t < 200; ++t) {
        float2 k1a, k1b, k2a, k2b, k3a, k3b, k4a, k4b, z1, z2;

        feval2(t2, a1, a2, om, nl2, bp0, bp1, k1a, k1b);
        z1 = make_float2(fmaf(hdt, k1a.x, a1.x), fmaf(hdt, k1a.y, a1.y));
        z2 = make_float2(fmaf(hdt, k1b.x, a2.x), fmaf(hdt, k1b.y, a2.y));
        feval2(t2, z1, z2, om, nl2, bp0, bp1, k2a, k2b);
        z1 = make_float2(fmaf(hdt, k2a.x, a1.x), fmaf(hdt, k2a.y, a1.y));
        z2 = make_float2(fmaf(hdt, k2b.x, a2.x), fmaf(hdt, k2b.y, a2.y));
        feval2(t2, z1, z2, om, nl2, bp0, bp1, k3a, k3b);
        z1 = make_float2(fmaf(dt, k3a.x, a1.x), fmaf(dt, k3a.y, a1.y));
        z2 = make_float2(fmaf(dt, k3b.x, a2.x), fmaf(dt, k3b.y, a2.y));
        feval2(t2, z1, z2, om, nl2, bp0, bp1, k4a, k4b);

        a1.x = fmaf(sdt, fmaf(2.0f, k2a.x + k3a.x, k1a.x + k4a.x), a1.x);
        a1.y = fmaf(sdt, fmaf(2.0f, k2a.y + k3a.y, k1a.y + k4a.y), a1.y);
        a2.x = fmaf(sdt, fmaf(2.0f, k2b.x + k3b.x, k1b.x + k4b.x), a2.x);
        a2.y = fmaf(sdt, fmaf(2.0f, k2b.y + k3b.y, k1b.y + k4b.y), a2.y);

        o1 += 65536;  // 2048 * 32
        o2 += 65536;
        if (lane < 32) {
            if (o1 < out_size) out[o1] = a1.x;
            if (o2 < out_size) out[o2] = a2.x;
        }
    }
}

extern "C" void kernel_launch(void* const* d_in, const int* in_sizes, int n_in,
                              void* d_out, int out_size, void* d_ws, size_t ws_size,
                              hipStream_t stream) {
    const float* A0r = (const float*)d_in[0];
    const float* A0i = (const float*)d_in[1];
    const float* omega = (const float*)d_in[2];
    const float* kappa = (const float*)d_in[3];
    const float* nln = (const float*)d_in[4];
    const float* params = (const float*)d_in[5];

    setup_kernel<<<1, 1024, 0, stream>>>(params, kappa);
    ode_kernel<<<1024, 64, 0, stream>>>(A0r, A0i, omega, nln,
                                        (float*)d_out, (long long)out_size);
}

// Round 5
// 395.341 us; speedup vs baseline: 1.1003x; 1.1003x over previous
//
#include <hip/hip_runtime.h>
#include <math.h>

#define NMODES 32
#define NPAIR 496
#define TAYLOR_N 12

// T2 matrix in module-scope device memory (d_ws may be zero-sized).
__device__ float2 g_T2[NMODES * NMODES];

__device__ __forceinline__ float2 cmul(float2 a, float2 b) {
    return make_float2(a.x * b.x - a.y * b.y, a.x * b.y + a.y * b.x);
}

// ---------------------------------------------------------------------------
// Setup kernel: one block of 1024 threads builds T2 (32x32 complex).
// (unchanged from the round-0/3 PASSING kernels)
// ---------------------------------------------------------------------------
__global__ __launch_bounds__(1024) void setup_kernel(const float* __restrict__ params,
                                                     const float* __restrict__ kappa) {
    __shared__ float2 X[NMODES][NMODES];
    __shared__ float2 R[NMODES][NMODES];
    __shared__ float2 W[NMODES][NMODES];
    __shared__ float2 Aug[NMODES][2 * NMODES];
    __shared__ int sh_s;
    __shared__ float sh_scale;
    __shared__ int sh_piv;
    __shared__ float2 sh_pivrec;

    const int tid = threadIdx.x;
    const int i = tid >> 5;
    const int j = tid & 31;

    // --- build H ---
    float2 h;
    if (i == j) {
        float d;
        if (i < 31) {
            d = params[2 * NPAIR + i];
        } else {
            d = 0.0f;
            for (int r = 0; r < 31; ++r) d -= params[2 * NPAIR + r];
        }
        h = make_float2(d, 0.0f);
    } else {
        int a = (i < j) ? i : j;
        int b = (i < j) ? j : i;
        int idx = 31 * a - (a * (a - 1)) / 2 + (b - a - 1);  // row-major triu
        float re = params[idx];
        float im = params[NPAIR + idx];
        h = (i < j) ? make_float2(re, im) : make_float2(re, -im);
    }
    X[i][j] = h;
    __syncthreads();

    // --- inf-norm (wave 0, parallel rows + shuffle max-reduce) ---
    if (tid < 32) {
        float s = 0.0f;
        for (int c = 0; c < NMODES; ++c) {
            float2 v = X[tid][c];
            s += sqrtf(v.x * v.x + v.y * v.y);
        }
        for (int off = 16; off > 0; off >>= 1)
            s = fmaxf(s, __shfl_down(s, off));
        if (tid == 0) {
            int sc_n = 0;
            float sc = 1.0f;
            while (s > 0.25f && sc_n < 40) { s *= 0.5f; sc *= 0.5f; ++sc_n; }
            sh_s = sc_n;
            sh_scale = sc;
        }
    }
    __syncthreads();

    // --- X = (i*H) * 2^{-s} ---
    {
        float sc = sh_scale;
        float2 v = X[i][j];
        X[i][j] = make_float2(-v.y * sc, v.x * sc);
    }
    __syncthreads();

    // --- Taylor via Horner: R = I; for k=N..1: R = I + (X*R)/k ---
    R[i][j] = make_float2((i == j) ? 1.0f : 0.0f, 0.0f);
    __syncthreads();
    for (int k = TAYLOR_N; k >= 1; --k) {
        float2 acc = make_float2(0.0f, 0.0f);
        for (int kk = 0; kk < NMODES; ++kk) {
            float2 a = X[i][kk];
            float2 b = R[kk][j];
            acc.x = fmaf(a.x, b.x, fmaf(-a.y, b.y, acc.x));
            acc.y = fmaf(a.x, b.y, fmaf(a.y, b.x, acc.y));
        }
        __syncthreads();
        float invk = 1.0f / (float)k;
        R[i][j] = make_float2(((i == j) ? 1.0f : 0.0f) + acc.x * invk, acc.y * invk);
        __syncthreads();
    }

    // --- squarings ---
    {
        int s = sh_s;
        for (int q = 0; q < s; ++q) {
            float2 acc = make_float2(0.0f, 0.0f);
            for (int kk = 0; kk < NMODES; ++kk) {
                float2 a = R[i][kk];
                float2 b = R[kk][j];
                acc.x = fmaf(a.x, b.x, fmaf(-a.y, b.y, acc.x));
                acc.y = fmaf(a.x, b.y, fmaf(a.y, b.x, acc.y));
            }
            __syncthreads();
            R[i][j] = acc;
            __syncthreads();
        }
    }

    // --- W = U^T U (no conjugation) ---
    {
        float2 acc = make_float2(0.0f, 0.0f);
        for (int kk = 0; kk < NMODES; ++kk) {
            float2 a = R[kk][i];
            float2 b = R[kk][j];
            acc.x = fmaf(a.x, b.x, fmaf(-a.y, b.y, acc.x));
            acc.y = fmaf(a.x, b.y, fmaf(a.y, b.x, acc.y));
        }
        W[i][j] = acc;
    }
    __syncthreads();

    // --- augmented [1.1 I - W | W] ---
    {
        float2 w = W[i][j];
        Aug[i][j] = make_float2(((i == j) ? 1.1f : 0.0f) - w.x, -w.y);
        Aug[i][j + NMODES] = w;
    }
    __syncthreads();

    // --- Gauss-Jordan with partial pivoting; right half -> mix ---
    for (int p = 0; p < NMODES; ++p) {
        if (tid < 32) {  // parallel argmax pivot search (wave 0)
            float2 v = Aug[tid][p];
            float mag = (tid >= p) ? (v.x * v.x + v.y * v.y) : -1.0f;
            int idx = tid;
            for (int off = 16; off > 0; off >>= 1) {
                float omg = __shfl_down(mag, off);
                int oi = __shfl_down(idx, off);
                if (omg > mag) { mag = omg; idx = oi; }
            }
            if (tid == 0) sh_piv = idx;
        }
        __syncthreads();
        int piv = sh_piv;
        if (piv != p && i == p) {
            float2 a0 = Aug[p][j], b0 = Aug[piv][j];
            float2 a1 = Aug[p][j + NMODES], b1 = Aug[piv][j + NMODES];
            Aug[p][j] = b0; Aug[piv][j] = a0;
            Aug[p][j + NMODES] = b1; Aug[piv][j + NMODES] = a1;
        }
        __syncthreads();
        if (tid == 0) {
            float2 d = Aug[p][p];
            float den = d.x * d.x + d.y * d.y;
            sh_pivrec = make_float2(d.x / den, -d.y / den);
        }
        __syncthreads();
        if (i == p) {
            float2 pr = sh_pivrec;
            Aug[p][j] = cmul(Aug[p][j], pr);
            Aug[p][j + NMODES] = cmul(Aug[p][j + NMODES], pr);
        }
        __syncthreads();
        float2 f = Aug[i][p];
        __syncthreads();
        if (i != p) {
            float2 rp0 = Aug[p][j];
            float2 rp1 = Aug[p][j + NMODES];
            float2 v0 = Aug[i][j];
            float2 v1 = Aug[i][j + NMODES];
            v0.x -= f.x * rp0.x - f.y * rp0.y;
            v0.y -= f.x * rp0.y + f.y * rp0.x;
            v1.x -= f.x * rp1.x - f.y * rp1.y;
            v1.y -= f.x * rp1.y + f.y * rp1.x;
            Aug[i][j] = v0;
            Aug[i][j + NMODES] = v1;
        }
        __syncthreads();
    }

    // --- T2 ---
    {
        float2 mix = Aug[i][j + NMODES];
        float kk2 = fabsf(kappa[i]) * fabsf(kappa[j]);
        float re = -kk2 * (((i == j) ? 0.5f : 0.0f) + mix.x);
        float im = -kk2 * mix.y;
        g_T2[i * NMODES + j] = make_float2(re, im);
    }
}

// ---------------------------------------------------------------------------
// Main ODE kernel — systolic XOR broadcast-TREE v4: 1 wave = 1 batch,
// 2048 waves (2/SIMD, round-3 grid), dependency depth flattened.
//
// Round-3 calibration: 334 VALU busy-cyc/wave-eval, 72% issue efficiency —
// the serial 30-step w->dpp->w Gray ring is a ~460-cyc critical path and the
// 2 phase-locked waves/SIMD stall on the same bubbles. Round 4 proved
// 1-wave/SIMD + 2-chain ILP is worse (compiler serialized the chains).
//
// This version: SAME lane decomposition, SAME four proven DPP patterns
// (quad_perm xor1/xor2/xor3, row_half_mirror=xor7, row_mirror=xor15), SAME
// bperm combine — but the 15 shuffled copies of z are an independent
// broadcast tree of depth <=3 instead of a serial ring:
//   L1 (from z):  w1 w2 w3 w7 wF
//   L2:           w4=w7^3 w5=w7^2 w6=w7^1   w8=wF^7 wC=wF^3 wD=wF^2 wE=wF^1
//   L3 (from w8): w9 wA wB
// and the 16 cfmas are spread over 4 independent accumulators. Critical path
// ~460 -> ~120 cyc << 668-cyc 2-wave busy floor, so TLP can fill the slots.
// t2 is indexed by plain xor mask (t2[s] = T2[row][p^s]) — reindex only.
// ---------------------------------------------------------------------------
template<int CTRL>
__device__ __forceinline__ float2 dppshuf(float2 v) {
    return make_float2(
        __int_as_float(__builtin_amdgcn_mov_dpp(__float_as_int(v.x), CTRL, 0xF, 0xF, true)),
        __int_as_float(__builtin_amdgcn_mov_dpp(__float_as_int(v.y), CTRL, 0xF, 0xF, true)));
}

#define QP_X1 0xB1   // quad_perm [1,0,3,2]   == xor 1
#define QP_X2 0x4E   // quad_perm [2,3,0,1]   == xor 2
#define QP_X3 0x1B   // quad_perm [3,2,1,0]   == xor 3
#define HM_X7 0x141  // row_half_mirror       == xor 7  (within 8)
#define RM_XF 0x140  // row_mirror            == xor 15 (within 16)

__device__ __forceinline__ void cfma(float2& acc, float2 c, float2 w) {
    acc.x = fmaf(c.x, w.x, fmaf(-c.y, w.y, acc.x));
    acc.y = fmaf(c.x, w.y, fmaf(c.y, w.x, acc.y));
}

__device__ __forceinline__ float bperm(int idx, float v) {
    return __int_as_float(__builtin_amdgcn_ds_bpermute(idx, __float_as_int(v)));
}

__device__ __forceinline__ float2 feval(const float2* __restrict__ t2,
                                        float2 z, float om, float nl2,
                                        int bp0, int bp1) {
    // --- broadcast tree: w[s].lane(p) = z.lane(p^s), depth <= 3 ---
    float2 w1 = dppshuf<QP_X1>(z);
    float2 w2 = dppshuf<QP_X2>(z);
    float2 w3 = dppshuf<QP_X3>(z);
    float2 w7 = dppshuf<HM_X7>(z);
    float2 wF = dppshuf<RM_XF>(z);
    float2 w4 = dppshuf<QP_X3>(w7);   // 7^3 = 4
    float2 w5 = dppshuf<QP_X2>(w7);   // 7^2 = 5
    float2 w6 = dppshuf<QP_X1>(w7);   // 7^1 = 6
    float2 w8 = dppshuf<HM_X7>(wF);   // 15^7 = 8
    float2 wC = dppshuf<QP_X3>(wF);   // 15^3 = 12
    float2 wD = dppshuf<QP_X2>(wF);   // 15^2 = 13
    float2 wE = dppshuf<QP_X1>(wF);   // 15^1 = 14
    float2 w9 = dppshuf<QP_X1>(w8);   // 8^1 = 9
    float2 wA = dppshuf<QP_X2>(w8);   // 8^2 = 10
    float2 wB = dppshuf<QP_X3>(w8);   // 8^3 = 11

    // --- 16 cfmas over 4 independent accumulators ---
    float2 a0 = make_float2(0.0f, 0.0f), a1 = make_float2(0.0f, 0.0f);
    float2 a2 = make_float2(0.0f, 0.0f), a3 = make_float2(0.0f, 0.0f);
    cfma(a0, t2[0],  z);
    cfma(a1, t2[1],  w1);
    cfma(a2, t2[2],  w2);
    cfma(a3, t2[3],  w3);
    cfma(a0, t2[4],  w4);
    cfma(a1, t2[5],  w5);
    cfma(a2, t2[6],  w6);
    cfma(a3, t2[7],  w7);
    cfma(a0, t2[8],  w8);
    cfma(a1, t2[9],  w9);
    cfma(a2, t2[10], wA);
    cfma(a3, t2[11], wB);
    cfma(a0, t2[12], wC);
    cfma(a1, t2[13], wD);
    cfma(a2, t2[14], wE);
    cfma(a3, t2[15], wF);

    float px = (a0.x + a1.x) + (a2.x + a3.x);
    float py = (a0.y + a1.y) + (a2.y + a3.y);
    // Gather the two block-partials of this lane's owned output row:
    // partial(out-lo[p]) in lanes p and 32+p; partial(out-hi[p]) in lanes
    // 16+p and 48+p. bp0 = 4*mstar, bp1 = bp0 + 128. (round-3 proven)
    float kx = bperm(bp0, px) + bperm(bp1, px);
    float ky = bperm(bp0, py) + bperm(bp1, py);

    // local nonlinear/frequency term for the held mode
    float wf = fmaf(nl2, fmaf(z.x, z.x, z.y * z.y), om);
    return make_float2(kx - wf * z.y, ky + wf * z.x);
}

__global__ __launch_bounds__(64) void ode_kernel(const float* __restrict__ A0r,
                                                 const float* __restrict__ A0i,
                                                 const float* __restrict__ omega,
                                                 const float* __restrict__ nln,
                                                 float* __restrict__ out,
                                                 long long out_size) {
    const int lane = threadIdx.x;
    const int r = lane >> 4;
    const int p = lane & 15;
    const int ho = r & 1;                       // output half this row computes
    const int hr = (r == 1 || r == 2) ? 1 : 0;  // held (ring) half
    const int mstar = 16 * hr + p;              // mode this lane owns
    const int bp0 = 4 * mstar;                  // bpermute: first partial
    const int bp1 = bp0 + 128;                  // bpermute: second partial
    const int b = blockIdx.x;

    // T2 block diagonal for this lane, indexed by xor mask s
    float2 t2[16];
    {
        const int row_g = 16 * ho + p;
#pragma unroll
        for (int s = 0; s < 16; ++s)
            t2[s] = g_T2[row_g * 32 + 16 * hr + (p ^ s)];
    }

    const float om = omega[mstar];
    const float nl = nln[0];
    const float nl2 = nl * nl;
    const float dt = 1.0f / 199.0f;
    const float hdt = 0.5f * dt;
    const float sdt = dt / 6.0f;

    // initial state for the held mode (one LDS bounce; lane l<32 owns mode l)
    __shared__ float2 ainit[32];
    if (lane < 32) {
        float2 v;
        if (lane < 24) v = make_float2(A0r[b * 24 + lane], A0i[b * 24 + lane]);
        else           v = make_float2(1.0f, 0.0f);
        ainit[lane] = v;
    }
    __syncthreads();
    float2 a = ainit[mstar];

    // t = 0 output (real plane only, guarded); lane l < 32 holds mode l
    long long o = (long long)b * 32 + lane;
    if (lane < 32 && o < out_size) out[o] = a.x;

    for (int t = 1; t < 200; ++t) {
        float2 k1 = feval(t2, a, om, nl2, bp0, bp1);
        float2 z = make_float2(fmaf(hdt, k1.x, a.x), fmaf(hdt, k1.y, a.y));
        float2 k2 = feval(t2, z, om, nl2, bp0, bp1);
        z = make_float2(fmaf(hdt, k2.x, a.x), fmaf(hdt, k2.y, a.y));
        float2 k3 = feval(t2, z, om, nl2, bp0, bp1);
        z = make_float2(fmaf(dt, k3.x, a.x), fmaf(dt, k3.y, a.y));
        float2 k4 = feval(t2, z, om, nl2, bp0, bp1);

        a.x = fmaf(sdt, fmaf(2.0f, k2.x + k3.x, k1.x + k4.x), a.x);
        a.y = fmaf(sdt, fmaf(2.0f, k2.y + k3.y, k1.y + k4.y), a.y);

        o += 65536;  // 2048 * 32
        if (lane < 32 && o < out_size) out[o] = a.x;
    }
}

extern "C" void kernel_launch(void* const* d_in, const int* in_sizes, int n_in,
                              void* d_out, int out_size, void* d_ws, size_t ws_size,
                              hipStream_t stream) {
    const float* A0r = (const float*)d_in[0];
    const float* A0i = (const float*)d_in[1];
    const float* omega = (const float*)d_in[2];
    const float* kappa = (const float*)d_in[3];
    const float* nln = (const float*)d_in[4];
    const float* params = (const float*)d_in[5];

    setup_kernel<<<1, 1024, 0, stream>>>(params, kappa);
    ode_kernel<<<2048, 64, 0, stream>>>(A0r, A0i, omega, nln,
                                        (float*)d_out, (long long)out_size);
}